// Round 1
// baseline (487.190 us; speedup 1.0000x reference)
//
#include <hip/hip_runtime.h>

#define NK 256            // IN == OUT == 256
#define ROWS_PER_ITER 128 // per block, per iteration (8 waves x 16 rows)
#define ITERS 4           // 131072 rows / (256 blocks * 128 rows)

typedef __attribute__((ext_vector_type(8))) short bf16x8;
typedef __attribute__((ext_vector_type(4))) float f32x4;

union BF8 { bf16x8 v; ushort u[8]; uint4 q; };

__device__ inline ushort f2bf(float f) {
    // round-to-nearest-even fp32 -> bf16 (inputs are finite normals)
    uint u = __float_as_uint(f);
    u += 0x7FFFu + ((u >> 16) & 1u);
    return (ushort)(u >> 16);
}

// Persistent block: grid = 256 (1 block/CU, LDS 132KB forces 1 anyway).
// Stage binarized W into LDS ONCE, sync once, then loop over 4 M-tiles with
// software prefetch (next A-tile loads issued before the MFMA chain).
// LDS layout [n][k] padded to 264 elems/row: 528B stride = 33 16B-slots,
// odd -> fb ds_read_b128 requests spread 8 dwords/bank (balanced).
__global__ __launch_bounds__(512, 2) void fused_binlinear(
    const float* __restrict__ x, const float* __restrict__ w, float* __restrict__ out)
{
    __shared__ ushort Bs[256 * 264];   // 132 KB

    const int tid = threadIdx.x;
    const int wv  = tid >> 6;
    const int ln  = tid & 63;
    const int m   = ln & 15;   // MFMA m / n / col lane index
    const int q   = ln >> 4;   // MFMA k-quad / row-quad

    // block covers rows [blockIdx.x*512, +512); wave wv owns 16-row slices
    const size_t rowBase = (size_t)blockIdx.x * (ROWS_PER_ITER * ITERS) + wv * 16;

    // ---- issue A loads for iter 0 FIRST so they fly during W staging ----
    const float4* xv = (const float4*)(x + (rowBase + m) * NK + q * 8);
    float4 a0[8], a1[8];
#pragma unroll
    for (int s = 0; s < 8; ++s) { a0[s] = xv[s * 8]; a1[s] = xv[s * 8 + 1]; }

    // ---- stage binarized W into LDS once (fold the >0.8 filter in) ----
#pragma unroll
    for (int i = 0; i < 16; ++i) {
        int cc = i * 512 + tid;          // 8-element chunk id, 8192 total
        int n  = cc >> 5;
        int kc = cc & 31;
        const float4* wp = (const float4*)(w + n * NK + kc * 8);
        float4 w0 = wp[0], w1 = wp[1];
        uint4 pk;
        pk.x = (w0.x > 0.8f ? 0x00003F80u : 0u) | (w0.y > 0.8f ? 0x3F800000u : 0u);
        pk.y = (w0.z > 0.8f ? 0x00003F80u : 0u) | (w0.w > 0.8f ? 0x3F800000u : 0u);
        pk.z = (w1.x > 0.8f ? 0x00003F80u : 0u) | (w1.y > 0.8f ? 0x3F800000u : 0u);
        pk.w = (w1.z > 0.8f ? 0x00003F80u : 0u) | (w1.w > 0.8f ? 0x3F800000u : 0u);
        *(uint4*)(&Bs[n * 264 + kc * 8]) = pk;
    }
    __syncthreads();   // the ONLY barrier — B is read-only from here on

    for (int it = 0; it < ITERS; ++it) {
        // ---- convert current A to bf16 fragments: lane holds A[m][k=s*32+q*8+j] ----
        bf16x8 fa[8];
#pragma unroll
        for (int s = 0; s < 8; ++s) {
            BF8 t;
            t.u[0] = f2bf(a0[s].x); t.u[1] = f2bf(a0[s].y);
            t.u[2] = f2bf(a0[s].z); t.u[3] = f2bf(a0[s].w);
            t.u[4] = f2bf(a1[s].x); t.u[5] = f2bf(a1[s].y);
            t.u[6] = f2bf(a1[s].z); t.u[7] = f2bf(a1[s].w);
            fa[s] = t.v;
        }

        // ---- prefetch next M-tile into the (now free) a0/a1 regs ----
        if (it + 1 < ITERS) {
            const float4* xn =
                (const float4*)(x + (rowBase + (size_t)(it + 1) * ROWS_PER_ITER + m) * NK + q * 8);
#pragma unroll
            for (int s = 0; s < 8; ++s) { a0[s] = xn[s * 8]; a1[s] = xn[s * 8 + 1]; }
        }

        // ---- MFMA: 8 k-steps x 16 n-tiles; B frag = Bs[n=t*16+m][k=s*32+q*8..] ----
        f32x4 acc[16];
#pragma unroll
        for (int t = 0; t < 16; ++t) acc[t] = (f32x4){0.f, 0.f, 0.f, 0.f};
#pragma unroll
        for (int s = 0; s < 8; ++s) {
#pragma unroll
            for (int t = 0; t < 16; ++t) {
                bf16x8 fb = *(const bf16x8*)(&Bs[(t * 16 + m) * 264 + s * 32 + q * 8]);
                acc[t] = __builtin_amdgcn_mfma_f32_16x16x32_bf16(fa[s], fb, acc[t], 0, 0, 0);
            }
        }

        // ---- fused row-mean: wave holds full rows; C/D layout col=m, row=q*4+r ----
        float rs[4];
#pragma unroll
        for (int r = 0; r < 4; ++r) {
            float s = 0.f;
#pragma unroll
            for (int t = 0; t < 16; ++t) s += acc[t][r];
            rs[r] = s;
        }
#pragma unroll
        for (int r = 0; r < 4; ++r) {
            rs[r] += __shfl_xor(rs[r], 1, 64);
            rs[r] += __shfl_xor(rs[r], 2, 64);
            rs[r] += __shfl_xor(rs[r], 4, 64);
            rs[r] += __shfl_xor(rs[r], 8, 64);
            rs[r] *= (1.0f / 256.0f);
        }

        // ---- store (nontemporal: don't let the write stream evict x from L3) ----
        const size_t row0 = rowBase + (size_t)it * ROWS_PER_ITER;
#pragma unroll
        for (int t = 0; t < 16; ++t) {
#pragma unroll
            for (int r = 0; r < 4; ++r) {
                __builtin_nontemporal_store(
                    acc[t][r] - rs[r],
                    &out[(row0 + q * 4 + r) * NK + t * 16 + m]);
            }
        }
    }
}

extern "C" void kernel_launch(void* const* d_in, const int* in_sizes, int n_in,
                              void* d_out, int out_size, void* d_ws, size_t ws_size,
                              hipStream_t stream) {
    const float* x  = (const float*)d_in[0];   // [131072, 256] fp32
    const float* w  = (const float*)d_in[1];   // [256, 256] fp32
    float* out      = (float*)d_out;           // [131072, 256] fp32
    const int M     = in_sizes[0] / NK;        // 131072
    fused_binlinear<<<M / (ROWS_PER_ITER * ITERS), 512, 0, stream>>>(x, w, out);
}

// Round 2
// 485.721 us; speedup vs baseline: 1.0030x; 1.0030x over previous
//
#include <hip/hip_runtime.h>

#define NK 256            // IN == OUT == 256
#define ROWS_PER_ITER 128 // per block, per iteration (8 waves x 16 rows)
#define ITERS 4           // 131072 rows / (256 blocks * 128 rows)

typedef __attribute__((ext_vector_type(8))) short bf16x8;
typedef __attribute__((ext_vector_type(4))) float f32x4;

union BF8 { bf16x8 v; ushort u[8]; uint4 q; };

__device__ inline ushort f2bf(float f) {
    // round-to-nearest-even fp32 -> bf16 (inputs are finite normals)
    uint u = __float_as_uint(f);
    u += 0x7FFFu + ((u >> 16) & 1u);
    return (ushort)(u >> 16);
}

// Persistent block: grid = 256 (1 block/CU, LDS 132KB forces 1 anyway).
// Stage binarized W into LDS ONCE, sync once, then loop over 4 M-tiles with
// software prefetch (next A-tile loads issued before the MFMA chain).
// Stores are PLAIN dword stores: the scattered per-lane pattern relies on L2
// write-coalescing (round-0 WRITE_SIZE was exactly 131073 KB). Nontemporal
// stores here caused partial-line RMW at HBM (+710 MB traffic) — never again.
__global__ __launch_bounds__(512, 2) void fused_binlinear(
    const float* __restrict__ x, const float* __restrict__ w, float* __restrict__ out)
{
    __shared__ ushort Bs[256 * 264];   // 132 KB

    const int tid = threadIdx.x;
    const int wv  = tid >> 6;
    const int ln  = tid & 63;
    const int m   = ln & 15;   // MFMA m / n / col lane index
    const int q   = ln >> 4;   // MFMA k-quad / row-quad

    // block covers rows [blockIdx.x*512, +512); wave wv owns 16-row slices
    const size_t rowBase = (size_t)blockIdx.x * (ROWS_PER_ITER * ITERS) + wv * 16;

    // ---- issue A loads for iter 0 FIRST so they fly during W staging ----
    const float4* xv = (const float4*)(x + (rowBase + m) * NK + q * 8);
    float4 a0[8], a1[8];
#pragma unroll
    for (int s = 0; s < 8; ++s) { a0[s] = xv[s * 8]; a1[s] = xv[s * 8 + 1]; }

    // ---- stage binarized W into LDS once (fold the >0.8 filter in) ----
#pragma unroll
    for (int i = 0; i < 16; ++i) {
        int cc = i * 512 + tid;          // 8-element chunk id, 8192 total
        int n  = cc >> 5;
        int kc = cc & 31;
        const float4* wp = (const float4*)(w + n * NK + kc * 8);
        float4 w0 = wp[0], w1 = wp[1];
        uint4 pk;
        pk.x = (w0.x > 0.8f ? 0x00003F80u : 0u) | (w0.y > 0.8f ? 0x3F800000u : 0u);
        pk.y = (w0.z > 0.8f ? 0x00003F80u : 0u) | (w0.w > 0.8f ? 0x3F800000u : 0u);
        pk.z = (w1.x > 0.8f ? 0x00003F80u : 0u) | (w1.y > 0.8f ? 0x3F800000u : 0u);
        pk.w = (w1.z > 0.8f ? 0x00003F80u : 0u) | (w1.w > 0.8f ? 0x3F800000u : 0u);
        *(uint4*)(&Bs[n * 264 + kc * 8]) = pk;
    }
    __syncthreads();   // the ONLY barrier — B is read-only from here on

    for (int it = 0; it < ITERS; ++it) {
        // ---- convert current A to bf16 fragments: lane holds A[m][k=s*32+q*8+j] ----
        bf16x8 fa[8];
#pragma unroll
        for (int s = 0; s < 8; ++s) {
            BF8 t;
            t.u[0] = f2bf(a0[s].x); t.u[1] = f2bf(a0[s].y);
            t.u[2] = f2bf(a0[s].z); t.u[3] = f2bf(a0[s].w);
            t.u[4] = f2bf(a1[s].x); t.u[5] = f2bf(a1[s].y);
            t.u[6] = f2bf(a1[s].z); t.u[7] = f2bf(a1[s].w);
            fa[s] = t.v;
        }

        // ---- prefetch next M-tile into the (now free) a0/a1 regs ----
        if (it + 1 < ITERS) {
            const float4* xn =
                (const float4*)(x + (rowBase + (size_t)(it + 1) * ROWS_PER_ITER + m) * NK + q * 8);
#pragma unroll
            for (int s = 0; s < 8; ++s) { a0[s] = xn[s * 8]; a1[s] = xn[s * 8 + 1]; }
        }

        // ---- MFMA: 8 k-steps x 16 n-tiles; B frag = Bs[n=t*16+m][k=s*32+q*8..] ----
        f32x4 acc[16];
#pragma unroll
        for (int t = 0; t < 16; ++t) acc[t] = (f32x4){0.f, 0.f, 0.f, 0.f};
#pragma unroll
        for (int s = 0; s < 8; ++s) {
#pragma unroll
            for (int t = 0; t < 16; ++t) {
                bf16x8 fb = *(const bf16x8*)(&Bs[(t * 16 + m) * 264 + s * 32 + q * 8]);
                acc[t] = __builtin_amdgcn_mfma_f32_16x16x32_bf16(fa[s], fb, acc[t], 0, 0, 0);
            }
        }

        // ---- fused row-mean: wave holds full rows; C/D layout col=m, row=q*4+r ----
        float rs[4];
#pragma unroll
        for (int r = 0; r < 4; ++r) {
            float s = 0.f;
#pragma unroll
            for (int t = 0; t < 16; ++t) s += acc[t][r];
            rs[r] = s;
        }
#pragma unroll
        for (int r = 0; r < 4; ++r) {
            rs[r] += __shfl_xor(rs[r], 1, 64);
            rs[r] += __shfl_xor(rs[r], 2, 64);
            rs[r] += __shfl_xor(rs[r], 4, 64);
            rs[r] += __shfl_xor(rs[r], 8, 64);
            rs[r] *= (1.0f / 256.0f);
        }

        // ---- store: plain dword stores, L2 coalesces the scattered pattern ----
        const size_t row0 = rowBase + (size_t)it * ROWS_PER_ITER;
#pragma unroll
        for (int t = 0; t < 16; ++t) {
#pragma unroll
            for (int r = 0; r < 4; ++r) {
                out[(row0 + q * 4 + r) * NK + t * 16 + m] = acc[t][r] - rs[r];
            }
        }
    }
}

extern "C" void kernel_launch(void* const* d_in, const int* in_sizes, int n_in,
                              void* d_out, int out_size, void* d_ws, size_t ws_size,
                              hipStream_t stream) {
    const float* x  = (const float*)d_in[0];   // [131072, 256] fp32
    const float* w  = (const float*)d_in[1];   // [256, 256] fp32
    float* out      = (float*)d_out;           // [131072, 256] fp32
    const int M     = in_sizes[0] / NK;        // 131072
    fused_binlinear<<<M / (ROWS_PER_ITER * ITERS), 512, 0, stream>>>(x, w, out);
}

// Round 3
// 247.383 us; speedup vs baseline: 1.9694x; 1.9634x over previous
//
#include <hip/hip_runtime.h>

#define NK  256   // IN == OUT == 256
#define LDN 264   // LDS row stride in ushort (528B -> 2-way bank aliasing, free per m136)

typedef __attribute__((ext_vector_type(8))) short bf16x8;
typedef __attribute__((ext_vector_type(4))) float f32x4;

union BF8 { bf16x8 v; ushort u[8]; uint4 q; };

__device__ inline ushort f2bf(float f) {
    // round-to-nearest-even fp32 -> bf16 (inputs are finite normals)
    uint u = __float_as_uint(f);
    u += 0x7FFFu + ((u >> 16) & 1u);
    return (ushort)(u >> 16);
}

// Round-0 grid (1024 blocks x 128 rows, one tile per block: proven exact-traffic,
// WRITE_SIZE == out bytes). New: B-tile staged in TWO n-halves of 66 KB LDS so
// 2 blocks/CU co-reside -> one block's MFMA overlaps the other's staging/stores.
// (Persistent-block variant inflated HBM traffic 4.5x via partial-line L2 thrash
//  -- reverted. Nontemporal stores ditto. Keep plain stores + burst-per-block.)
__global__ __launch_bounds__(512, 4) void fused_binlinear(
    const float* __restrict__ x, const float* __restrict__ w, float* __restrict__ out)
{
    __shared__ ushort Bs[128 * LDN];   // 66 KB -> 2 blocks/CU (160 KB budget)

    const int tid = threadIdx.x;
    const int wv  = tid >> 6;
    const int ln  = tid & 63;
    const int m   = ln & 15;   // MFMA m / n / col lane index
    const int q   = ln >> 4;   // MFMA k-quad / row-quad

    const int row0 = blockIdx.x * 128 + wv * 16;

    // ---- A loads issued first: 16 rows x 256 k fp32, fly during W staging ----
    const float4* xv = (const float4*)(x + (size_t)(row0 + m) * NK + q * 8);
    float4 a0[8], a1[8];
#pragma unroll
    for (int s = 0; s < 8; ++s) { a0[s] = xv[s * 8]; a1[s] = xv[s * 8 + 1]; }

    f32x4 acc[16];
#pragma unroll
    for (int t = 0; t < 16; ++t) acc[t] = (f32x4){0.f, 0.f, 0.f, 0.f};
    bf16x8 fa[8];

#pragma unroll
    for (int p = 0; p < 2; ++p) {
        if (p) __syncthreads();   // all waves done reading pass-0 Bs

        // ---- stage binarized W rows [p*128, p*128+128) into LDS ----
#pragma unroll
        for (int i = 0; i < 8; ++i) {
            int cc = i * 512 + tid;      // 8-elem chunk id, 4096 per pass
            int n  = cc >> 5;            // 0..127 (local)
            int kc = cc & 31;
            const float4* wp = (const float4*)(w + (size_t)(p * 128 + n) * NK + kc * 8);
            float4 w0 = wp[0], w1 = wp[1];
            uint4 pk;
            pk.x = (w0.x > 0.8f ? 0x00003F80u : 0u) | (w0.y > 0.8f ? 0x3F800000u : 0u);
            pk.y = (w0.z > 0.8f ? 0x00003F80u : 0u) | (w0.w > 0.8f ? 0x3F800000u : 0u);
            pk.z = (w1.x > 0.8f ? 0x00003F80u : 0u) | (w1.y > 0.8f ? 0x3F800000u : 0u);
            pk.w = (w1.z > 0.8f ? 0x00003F80u : 0u) | (w1.w > 0.8f ? 0x3F800000u : 0u);
            *(uint4*)(&Bs[n * LDN + kc * 8]) = pk;
        }
        __syncthreads();

        // ---- convert A once (x loads landed during pass-0 staging) ----
        if (p == 0) {
#pragma unroll
            for (int s = 0; s < 8; ++s) {
                BF8 t;
                t.u[0] = f2bf(a0[s].x); t.u[1] = f2bf(a0[s].y);
                t.u[2] = f2bf(a0[s].z); t.u[3] = f2bf(a0[s].w);
                t.u[4] = f2bf(a1[s].x); t.u[5] = f2bf(a1[s].y);
                t.u[6] = f2bf(a1[s].z); t.u[7] = f2bf(a1[s].w);
                fa[s] = t.v;
            }
        }

        // ---- MFMA: 8 k-steps x 8 n-tiles this pass ----
#pragma unroll
        for (int s = 0; s < 8; ++s) {
#pragma unroll
            for (int t = 0; t < 8; ++t) {
                bf16x8 fb = *(const bf16x8*)(&Bs[(t * 16 + m) * LDN + s * 32 + q * 8]);
                acc[p * 8 + t] =
                    __builtin_amdgcn_mfma_f32_16x16x32_bf16(fa[s], fb, acc[p * 8 + t], 0, 0, 0);
            }
        }
    }

    // ---- fused row-mean: wave holds full rows; C/D layout col=m, row=q*4+r ----
    float rs[4];
#pragma unroll
    for (int r = 0; r < 4; ++r) {
        float s = 0.f;
#pragma unroll
        for (int t = 0; t < 16; ++t) s += acc[t][r];
        rs[r] = s;
    }
#pragma unroll
    for (int r = 0; r < 4; ++r) {
        rs[r] += __shfl_xor(rs[r], 1, 64);
        rs[r] += __shfl_xor(rs[r], 2, 64);
        rs[r] += __shfl_xor(rs[r], 4, 64);
        rs[r] += __shfl_xor(rs[r], 8, 64);
        rs[r] *= (1.0f / 256.0f);
    }

    // ---- store: plain dword stores in a tight per-block burst (L2 coalesces) ----
#pragma unroll
    for (int t = 0; t < 16; ++t) {
#pragma unroll
        for (int r = 0; r < 4; ++r) {
            out[(size_t)(row0 + q * 4 + r) * NK + t * 16 + m] = acc[t][r] - rs[r];
        }
    }
}

extern "C" void kernel_launch(void* const* d_in, const int* in_sizes, int n_in,
                              void* d_out, int out_size, void* d_ws, size_t ws_size,
                              hipStream_t stream) {
    const float* x  = (const float*)d_in[0];   // [131072, 256] fp32
    const float* w  = (const float*)d_in[1];   // [256, 256] fp32
    float* out      = (float*)d_out;           // [131072, 256] fp32
    const int M     = in_sizes[0] / NK;        // 131072
    fused_binlinear<<<M / 128, 512, 0, stream>>>(x, w, out);
}